// Round 6
// baseline (61.646 us; speedup 1.0000x reference)
//
#include <hip/hip_runtime.h>
#include <hip/hip_bf16.h>
#include <math.h>

#define BATCH 4096
#define NROWS 8192
#define DIM 256
#define NP 64                         // 128-row panels
#define NBLK (NP * (NP + 1) / 2)      // 2080 triangular tiles
#define GRID_B 512                    // persistent blocks (2 per CU)

// zn scale c with c^2 = 2*log2(e): sim_scaled = c^2*cos = 2*log2e*cos,
// so exp2(sim_scaled) = e^{2 cos} directly.
#define ZN_SCALE 1.698643600577466f   // sqrt(2.8853900817779268)
#define LN2F 0.6931471805599453f

typedef __attribute__((ext_vector_type(4))) float f32x4;
typedef __attribute__((ext_vector_type(8))) short short8;

#if defined(__has_builtin)
#if __has_builtin(__builtin_amdgcn_exp2f)
#define EXP2F(x) __builtin_amdgcn_exp2f(x)
#endif
#endif
#ifndef EXP2F
#define EXP2F(x) __expf(LN2F * (x))
#endif

static __device__ __forceinline__ unsigned short f2bf(float x) {
    __hip_bfloat16 h = __float2bfloat16(x);
    return *reinterpret_cast<unsigned short*>(&h);
}
static __device__ __forceinline__ float bf2f(unsigned short u) {
    union { unsigned int i; float f; } x;
    x.i = ((unsigned int)u) << 16;
    return x.f;
}

// ---------------------------------------------------------------------------
// Kernel A: concat + L2-normalize + scale, write row-major (zn) AND
// MFMA-fragment-packed (pk) layouts.
// pk: element (row r, dim e) lives at granule g*8 + (e&7), where
//     g = ((r>>4)*8 + (e>>5))*64 + ((e&31)>>3)*16 + (r&15)
// ---------------------------------------------------------------------------
__global__ void normalize_kernel(const float* __restrict__ z_i,
                                 const float* __restrict__ z_j,
                                 unsigned short* __restrict__ zn,
                                 unsigned short* __restrict__ pk) {
    int wid  = (blockIdx.x * blockDim.x + threadIdx.x) >> 6;   // row
    int lane = threadIdx.x & 63;
    if (wid >= NROWS) return;
    const float* src = (wid < BATCH) ? (z_i + (size_t)wid * DIM)
                                     : (z_j + (size_t)(wid - BATCH) * DIM);
    float4 v = reinterpret_cast<const float4*>(src)[lane];
    float ss = v.x * v.x + v.y * v.y + v.z * v.z + v.w * v.w;
#pragma unroll
    for (int m = 1; m < 64; m <<= 1) ss += __shfl_xor(ss, m);
    float inv = ZN_SCALE / fmaxf(sqrtf(ss), 1e-8f);
    ushort4 o;
    o.x = f2bf(v.x * inv);
    o.y = f2bf(v.y * inv);
    o.z = f2bf(v.z * inv);
    o.w = f2bf(v.w * inv);
    reinterpret_cast<ushort4*>(zn + (size_t)wid * DIM)[lane] = o;
    size_t g = ((size_t)(wid >> 4) * 8 + (lane >> 3)) * 64
             + ((lane & 7) >> 1) * 16 + (wid & 15);
    *reinterpret_cast<ushort4*>(pk + g * 8 + (lane & 1) * 4) = o;
}

// ---------------------------------------------------------------------------
// Kernel B: symmetric fused sim-GEMM + sum-of-exp, persistent blocks.
// 512 blocks x ~4 tiles each; tiles are upper-triangle (p,q) 128x128 panels.
// Continuous double-buffered global_load_lds pipeline ACROSS tiles: at a
// tile's last K-step the next tile's step-0 is staged, so prologue latency
// is paid once per block. Epilogue overlaps the in-flight next-tile loads.
// part layout: [NROWS][NP] for coalesced rowloss reads.
// ---------------------------------------------------------------------------
typedef const __attribute__((address_space(1))) unsigned int g_u32;
typedef __attribute__((address_space(3))) unsigned int l_u32;

__device__ __forceinline__ void unrank_tile(int t, int& p, int& q) {
    int pp = (int)((129.0f - sqrtf(16641.0f - 8.0f * (float)t)) * 0.5f);
    pp = pp < 0 ? 0 : (pp > 63 ? 63 : pp);
    while (pp > 0 && t < pp * (129 - pp) / 2) --pp;
    while (pp < 63 && t >= (pp + 1) * (128 - pp) / 2) ++pp;
    p = pp;
    q = pp + (t - pp * (129 - pp) / 2);
}

__device__ __forceinline__ void stage_step(const char* __restrict__ pkb,
                                           char* lds, int wave, int lane,
                                           int p, int q, int ks, int buf) {
#pragma unroll
    for (int i = 0; i < 8; ++i) {
        int id  = wave * 8 + i;
        int isB = id >> 4;               // waves 0,1 stage A(p); 2,3 stage B(q)
        int rtl = (id >> 1) & 7;         // local row-tile 0..7
        int kf  = id & 1;                // k-frag within BK=64
        int rtbase = (isB ? q : p) * 8;
        size_t grow = (size_t)(rtbase + rtl) * 8 + ks * 2 + kf;
        const char* src = pkb + grow * 1024 + (size_t)lane * 16;
        char* dst = lds + buf * 32768 + isB * 16384 + (rtl * 2 + kf) * 1024;
        __builtin_amdgcn_global_load_lds((g_u32*)src, (l_u32*)dst, 16, 0, 0);
    }
}

__global__ __launch_bounds__(256, 2)
void simloss_kernel(const unsigned short* __restrict__ pk,
                    float* __restrict__ part /* [NROWS][NP] */) {
    __shared__ __attribute__((aligned(16))) unsigned char lds[65536];
    __shared__ __attribute__((aligned(16))) float red[512];
    int wave = threadIdx.x >> 6;
    int lane = threadIdx.x & 63;
    int lr = lane & 15;                  // fragment col
    int lk = lane >> 4;                  // fragment row group
    int wr = wave >> 1, wc = wave & 1;
    int wr4 = wr * 4, wc4 = wc * 4;
    const char* pkb = (const char*)pk;

    int t = blockIdx.x;
    int p, q;
    unrank_tile(t, p, q);

    f32x4 acc[4][4];
#pragma unroll
    for (int m = 0; m < 4; ++m)
#pragma unroll
        for (int n = 0; n < 4; ++n) acc[m][n] = (f32x4){0.f, 0.f, 0.f, 0.f};

    stage_step(pkb, (char*)lds, wave, lane, p, q, 0, 0);
    int gbuf = 0;

#pragma unroll 1
    for (;;) {
        bool more = (t + GRID_B < NBLK);
        int np = 0, nq = 0;
        if (more) unrank_tile(t + GRID_B, np, nq);

#pragma unroll
        for (int s = 0; s < 4; ++s) {
            if (s < 3) {
                stage_step(pkb, (char*)lds, wave, lane, p, q, s + 1, gbuf ^ 1);
                asm volatile("s_waitcnt vmcnt(8)" ::: "memory");
            } else if (more) {
                stage_step(pkb, (char*)lds, wave, lane, np, nq, 0, gbuf ^ 1);
                asm volatile("s_waitcnt vmcnt(8)" ::: "memory");
            } else {
                asm volatile("s_waitcnt vmcnt(0)" ::: "memory");
            }
            __builtin_amdgcn_s_barrier();

            const unsigned short* Ab = (const unsigned short*)(lds + gbuf * 32768);
            const unsigned short* Bb = (const unsigned short*)(lds + gbuf * 32768 + 16384);
#pragma unroll
            for (int kf = 0; kf < 2; ++kf) {
                short8 a[4], b[4];
#pragma unroll
                for (int m = 0; m < 4; ++m)
                    a[m] = *(const short8*)(Ab + ((wr4 + m) * 2 + kf) * 512 + lane * 8);
#pragma unroll
                for (int n = 0; n < 4; ++n)
                    b[n] = *(const short8*)(Bb + ((wc4 + n) * 2 + kf) * 512 + lane * 8);
#pragma unroll
                for (int m = 0; m < 4; ++m)
#pragma unroll
                    for (int n = 0; n < 4; ++n)
                        acc[m][n] = __builtin_amdgcn_mfma_f32_16x16x32_bf16(
                            a[m], b[n], acc[m][n], 0, 0, 0);
            }
            if (s < 3) {                  // end-of-step barrier (last step's is
                asm volatile("" ::: "memory");   //  folded into epilogue sync)
                __builtin_amdgcn_s_barrier();
            }
            gbuf ^= 1;
        }

        // ---- epilogue: exp2, diag-zero, row partials + (p!=q) col partials
        // (next tile's step-0 loads are in flight underneath this)
        int R0 = p * 128 + wr * 64;
        int C0 = q * 128 + wc * 64;
        float dacc[4][4];
#pragma unroll
        for (int m = 0; m < 4; ++m)
#pragma unroll
            for (int j = 0; j < 4; ++j) dacc[m][j] = 0.f;
        float cacc[4] = {0.f, 0.f, 0.f, 0.f};

#pragma unroll
        for (int m = 0; m < 4; ++m) {
            int gr = R0 + m * 16;
#pragma unroll
            for (int n = 0; n < 4; ++n) {
                int gc = C0 + n * 16;
                bool diagf = (gr == gc);      // uniform per fragment
                float cs_ = 0.f;
#pragma unroll
                for (int j = 0; j < 4; ++j) {
                    float e = EXP2F(acc[m][n][j]);
                    if (diagf && lr == lk * 4 + j) e = 0.0f;
                    dacc[m][j] += e;
                    cs_ += e;
                }
                cacc[n] += cs_;
                acc[m][n] = (f32x4){0.f, 0.f, 0.f, 0.f};
            }
        }

#pragma unroll
        for (int m = 0; m < 4; ++m)
#pragma unroll
            for (int j = 0; j < 4; ++j) {
                float v = dacc[m][j];
                v += __shfl_xor(v, 1);
                v += __shfl_xor(v, 2);
                v += __shfl_xor(v, 4);
                v += __shfl_xor(v, 8);
                if (lr == 0) red[wave * 64 + m * 16 + lk * 4 + j] = v;
            }
        if (p != q) {
#pragma unroll
            for (int n = 0; n < 4; ++n) {
                float c = cacc[n];
                c += __shfl_xor(c, 16);
                c += __shfl_xor(c, 32);
                if (lk == 0) red[256 + wave * 64 + n * 16 + lr] = c;
            }
        }
        // combined epilogue + pipeline barrier: waits LDS ops (incl. this
        // tile's ds_reads) but leaves next tile's vmcnt loads in flight.
        asm volatile("s_waitcnt lgkmcnt(0)\n\ts_barrier" ::: "memory");

        int tid = threadIdx.x;
        if (tid < 128) {                 // row pieces: piece q of panel-p rows
            int wrh = tid >> 6, loc = tid & 63;
            float v = red[(wrh * 2 + 0) * 64 + loc] + red[(wrh * 2 + 1) * 64 + loc];
            part[(size_t)(p * 128 + tid) * NP + q] = v;
        } else if (p != q) {             // col pieces: piece p of panel-q rows
            int i2 = tid - 128;
            int wch = i2 >> 6, loc = i2 & 63;
            float v = red[256 + wch * 64 + loc] + red[256 + (2 + wch) * 64 + loc];
            part[(size_t)(q * 128 + i2) * NP + p] = v;
        }

        if (!more) break;
        t += GRID_B; p = np; q = nq;
    }
}

// ---------------------------------------------------------------------------
// Kernel C: per-row loss: log(sum of 64 pieces) - pos_dot*ln2
// (zn is scaled so dot = 2*log2e*cos; 2*cos = dot*ln2)
// ---------------------------------------------------------------------------
__global__ void rowloss_kernel(const unsigned short* __restrict__ zn,
                               const float* __restrict__ part,
                               float* __restrict__ cpart) {
    int wave = threadIdx.x >> 6;
    int lane = threadIdx.x & 63;
    float wsum = 0.0f;
#pragma unroll 1
    for (int it = 0; it < 8; ++it) {
        int r = blockIdx.x * 32 + wave * 8 + it;
        ushort4 za = reinterpret_cast<const ushort4*>(zn + (size_t)r * DIM)[lane];
        ushort4 zb = reinterpret_cast<const ushort4*>(zn + (size_t)(r ^ BATCH) * DIM)[lane];
        float dot = bf2f(za.x) * bf2f(zb.x) + bf2f(za.y) * bf2f(zb.y) +
                    bf2f(za.z) * bf2f(zb.z) + bf2f(za.w) * bf2f(zb.w);
#pragma unroll
        for (int m = 1; m < 64; m <<= 1) dot += __shfl_xor(dot, m);
        float den = part[(size_t)r * NP + lane];
#pragma unroll
        for (int m = 1; m < 64; m <<= 1) den += __shfl_xor(den, m);
        if (lane == 0) wsum += logf(den) - dot * LN2F;
    }
    __shared__ float red[4];
    if (lane == 0) red[wave] = wsum;
    __syncthreads();
    if (threadIdx.x == 0)
        cpart[blockIdx.x] = red[0] + red[1] + red[2] + red[3];
}

// ---------------------------------------------------------------------------
// Kernel D: final reduction of 256 block partials -> scalar loss / n
// ---------------------------------------------------------------------------
__global__ void final_kernel(const float* __restrict__ cpart,
                             float* __restrict__ out) {
    int lane = threadIdx.x & 63;
    int wave = threadIdx.x >> 6;
    double v = (double)cpart[threadIdx.x];
#pragma unroll
    for (int m = 1; m < 64; m <<= 1) v += __shfl_xor(v, m);
    __shared__ double red[4];
    if (lane == 0) red[wave] = v;
    __syncthreads();
    if (threadIdx.x == 0)
        out[0] = (float)((red[0] + red[1] + red[2] + red[3]) / (double)NROWS);
}

// ---------------------------------------------------------------------------
extern "C" void kernel_launch(void* const* d_in, const int* in_sizes, int n_in,
                              void* d_out, int out_size, void* d_ws, size_t ws_size,
                              hipStream_t stream) {
    const float* z_i = (const float*)d_in[0];
    const float* z_j = (const float*)d_in[1];
    float* out = (float*)d_out;
    char* ws = (char*)d_ws;

    unsigned short* zn = (unsigned short*)ws;                              // 4 MB
    unsigned short* pk = (unsigned short*)(ws + (size_t)NROWS * DIM * 2);  // 4 MB
    float* part  = (float*)(ws + 2 * (size_t)NROWS * DIM * 2);             // 2 MB
    float* cpart = (float*)(ws + 2 * (size_t)NROWS * DIM * 2
                               + (size_t)NROWS * NP * 4);

    normalize_kernel<<<NROWS / 4, 256, 0, stream>>>(z_i, z_j, zn, pk);
    simloss_kernel<<<GRID_B, 256, 0, stream>>>(pk, part);
    rowloss_kernel<<<NROWS / 32, 256, 0, stream>>>(zn, part, cpart);
    final_kernel<<<1, 256, 0, stream>>>(cpart, out);
}

// Round 7
// 59.591 us; speedup vs baseline: 1.0345x; 1.0345x over previous
//
#include <hip/hip_runtime.h>
#include <hip/hip_bf16.h>
#include <math.h>

#define BATCH 4096
#define NROWS 8192
#define DIM 256
#define NP 64                         // 128-row panels
#define NBLK (NP * (NP + 1) / 2)      // 2080 triangular tiles
#define GRID_B 1040                   // exactly 2 tiles per block
#define NSTEPS 8                      // K steps per tile (BK=32)

// zn scale c with c^2 = 2*log2(e): sim_scaled = c^2*cos = 2*log2e*cos,
// so exp2(sim_scaled) = e^{2 cos} directly.
#define ZN_SCALE 1.698643600577466f   // sqrt(2.8853900817779268)
#define LN2F 0.6931471805599453f

typedef __attribute__((ext_vector_type(4))) float f32x4;
typedef __attribute__((ext_vector_type(8))) short short8;

#if defined(__has_builtin)
#if __has_builtin(__builtin_amdgcn_exp2f)
#define EXP2F(x) __builtin_amdgcn_exp2f(x)
#endif
#endif
#ifndef EXP2F
#define EXP2F(x) __expf(LN2F * (x))
#endif

static __device__ __forceinline__ unsigned short f2bf(float x) {
    __hip_bfloat16 h = __float2bfloat16(x);
    return *reinterpret_cast<unsigned short*>(&h);
}
static __device__ __forceinline__ float bf2f(unsigned short u) {
    union { unsigned int i; float f; } x;
    x.i = ((unsigned int)u) << 16;
    return x.f;
}

// ---------------------------------------------------------------------------
// Kernel A: concat + L2-normalize + scale, write row-major (zn) AND
// MFMA-fragment-packed (pk) layouts.
// pk: element (row r, dim e) lives at granule g*8 + (e&7), where
//     g = ((r>>4)*8 + (e>>5))*64 + ((e&31)>>3)*16 + (r&15)
// ---------------------------------------------------------------------------
__global__ void normalize_kernel(const float* __restrict__ z_i,
                                 const float* __restrict__ z_j,
                                 unsigned short* __restrict__ zn,
                                 unsigned short* __restrict__ pk) {
    int wid  = (blockIdx.x * blockDim.x + threadIdx.x) >> 6;   // row
    int lane = threadIdx.x & 63;
    if (wid >= NROWS) return;
    const float* src = (wid < BATCH) ? (z_i + (size_t)wid * DIM)
                                     : (z_j + (size_t)(wid - BATCH) * DIM);
    float4 v = reinterpret_cast<const float4*>(src)[lane];
    float ss = v.x * v.x + v.y * v.y + v.z * v.z + v.w * v.w;
#pragma unroll
    for (int m = 1; m < 64; m <<= 1) ss += __shfl_xor(ss, m);
    float inv = ZN_SCALE / fmaxf(sqrtf(ss), 1e-8f);
    ushort4 o;
    o.x = f2bf(v.x * inv);
    o.y = f2bf(v.y * inv);
    o.z = f2bf(v.z * inv);
    o.w = f2bf(v.w * inv);
    reinterpret_cast<ushort4*>(zn + (size_t)wid * DIM)[lane] = o;
    size_t g = ((size_t)(wid >> 4) * 8 + (lane >> 3)) * 64
             + ((lane & 7) >> 1) * 16 + (wid & 15);
    *reinterpret_cast<ushort4*>(pk + g * 8 + (lane & 1) * 4) = o;
}

// ---------------------------------------------------------------------------
// Kernel B: symmetric fused sim-GEMM + sum-of-exp, persistent blocks.
// 1040 blocks x exactly 2 tiles; tiles = upper-triangle (p,q) 128x128 panels.
// BK=32: per K-step stage A[128x32]+B[128x32] (16 KB) double-buffered
// (32 KB LDS + 2 KB reduce scratch -> 4 blocks/CU, 16 waves/CU).
// Counted vmcnt(4) keeps the staging stream in flight across barriers and
// across tiles (step-0 of the next tile staged at step 7).
// part layout: [NP][NROWS] so epilogue writes are fully coalesced.
// ---------------------------------------------------------------------------
typedef const __attribute__((address_space(1))) unsigned int g_u32;
typedef __attribute__((address_space(3))) unsigned int l_u32;

__device__ __forceinline__ void unrank_tile(int t, int& p, int& q) {
    int pp = (int)((129.0f - sqrtf(16641.0f - 8.0f * (float)t)) * 0.5f);
    pp = pp < 0 ? 0 : (pp > 63 ? 63 : pp);
    while (pp > 0 && t < pp * (129 - pp) / 2) --pp;
    while (pp < 63 && t >= (pp + 1) * (128 - pp) / 2) ++pp;
    p = pp;
    q = pp + (t - pp * (129 - pp) / 2);
}

// Stage one BK=32 step: 16 granule-rows (A frags 0..7, B frags 0..7),
// 4 global_load_lds per wave.
__device__ __forceinline__ void stage_step(const char* __restrict__ pkb,
                                           char* lds, int wave, int lane,
                                           int p, int q, int ks, int buf) {
#pragma unroll
    for (int i = 0; i < 4; ++i) {
        int id  = wave * 4 + i;          // 0..15
        int isB = id >> 3;               // waves 0,1 stage A(p); 2,3 stage B(q)
        int rtl = id & 7;                // local row-tile 0..7
        size_t grow = (size_t)((isB ? q : p) * 8 + rtl) * 8 + ks;
        const char* src = pkb + grow * 1024 + (size_t)lane * 16;
        char* dst = lds + buf * 16384 + isB * 8192 + rtl * 1024;
        __builtin_amdgcn_global_load_lds((g_u32*)src, (l_u32*)dst, 16, 0, 0);
    }
}

__global__ __launch_bounds__(256, 4)
void simloss_kernel(const unsigned short* __restrict__ pk,
                    float* __restrict__ part /* [NP][NROWS] */) {
    __shared__ __attribute__((aligned(16))) unsigned char lds[32768];
    __shared__ __attribute__((aligned(16))) float red[512];
    int wave = threadIdx.x >> 6;
    int lane = threadIdx.x & 63;
    int lr = lane & 15;                  // fragment col
    int lk = lane >> 4;                  // fragment row group
    int wr = wave >> 1, wc = wave & 1;
    int wr4 = wr * 4, wc4 = wc * 4;
    const char* pkb = (const char*)pk;

    int t = blockIdx.x;
    int p, q;
    unrank_tile(t, p, q);

    f32x4 acc[4][4];
#pragma unroll
    for (int m = 0; m < 4; ++m)
#pragma unroll
        for (int n = 0; n < 4; ++n) acc[m][n] = (f32x4){0.f, 0.f, 0.f, 0.f};

    stage_step(pkb, (char*)lds, wave, lane, p, q, 0, 0);
    int gbuf = 0;

#pragma unroll 1
    for (int ti = 0;; ++ti) {
        bool more = (ti == 0);           // exactly 2 tiles per block
        int np = 0, nq = 0;
        if (more) unrank_tile(t + GRID_B, np, nq);

#pragma unroll 1
        for (int s = 0; s < NSTEPS; ++s) {
            if (s < NSTEPS - 1) {
                stage_step(pkb, (char*)lds, wave, lane, p, q, s + 1, gbuf ^ 1);
                asm volatile("s_waitcnt vmcnt(4)" ::: "memory");
            } else if (more) {
                stage_step(pkb, (char*)lds, wave, lane, np, nq, 0, gbuf ^ 1);
                asm volatile("s_waitcnt vmcnt(4)" ::: "memory");
            } else {
                asm volatile("s_waitcnt vmcnt(0)" ::: "memory");
            }
            __builtin_amdgcn_s_barrier();

            const unsigned short* Ab = (const unsigned short*)(lds + gbuf * 16384);
            const unsigned short* Bb = (const unsigned short*)(lds + gbuf * 16384 + 8192);
            short8 a[4], b[4];
#pragma unroll
            for (int m = 0; m < 4; ++m)
                a[m] = *(const short8*)(Ab + (wr4 + m) * 512 + lane * 8);
#pragma unroll
            for (int n = 0; n < 4; ++n)
                b[n] = *(const short8*)(Bb + (wc4 + n) * 512 + lane * 8);
#pragma unroll
            for (int m = 0; m < 4; ++m)
#pragma unroll
                for (int n = 0; n < 4; ++n)
                    acc[m][n] = __builtin_amdgcn_mfma_f32_16x16x32_bf16(
                        a[m], b[n], acc[m][n], 0, 0, 0);

            if (s < NSTEPS - 1) {        // end-of-step barrier (last step's is
                asm volatile("" ::: "memory");   // folded into epilogue sync)
                __builtin_amdgcn_s_barrier();
            }
            gbuf ^= 1;
        }

        // ---- epilogue: exp2, diag-zero, row partials + (p!=q) col partials
        // (next tile's step-0 loads are in flight underneath this)
        int R0 = p * 128 + wr * 64;
        int C0 = q * 128 + wc * 64;
        float dacc[4][4];
#pragma unroll
        for (int m = 0; m < 4; ++m)
#pragma unroll
            for (int j = 0; j < 4; ++j) dacc[m][j] = 0.f;
        float cacc[4] = {0.f, 0.f, 0.f, 0.f};

#pragma unroll
        for (int m = 0; m < 4; ++m) {
            int gr = R0 + m * 16;
#pragma unroll
            for (int n = 0; n < 4; ++n) {
                int gc = C0 + n * 16;
                bool diagf = (gr == gc);      // uniform per fragment
                float cs_ = 0.f;
#pragma unroll
                for (int j = 0; j < 4; ++j) {
                    float e = EXP2F(acc[m][n][j]);
                    if (diagf && lr == lk * 4 + j) e = 0.0f;
                    dacc[m][j] += e;
                    cs_ += e;
                }
                cacc[n] += cs_;
                acc[m][n] = (f32x4){0.f, 0.f, 0.f, 0.f};
            }
        }

#pragma unroll
        for (int m = 0; m < 4; ++m)
#pragma unroll
            for (int j = 0; j < 4; ++j) {
                float v = dacc[m][j];
                v += __shfl_xor(v, 1);
                v += __shfl_xor(v, 2);
                v += __shfl_xor(v, 4);
                v += __shfl_xor(v, 8);
                if (lr == 0) red[wave * 64 + m * 16 + lk * 4 + j] = v;
            }
        if (p != q) {
#pragma unroll
            for (int n = 0; n < 4; ++n) {
                float c = cacc[n];
                c += __shfl_xor(c, 16);
                c += __shfl_xor(c, 32);
                if (lk == 0) red[256 + wave * 64 + n * 16 + lr] = c;
            }
        }
        // combined epilogue + pipeline barrier: waits LDS ops only; next
        // tile's vmcnt loads stay in flight.
        asm volatile("s_waitcnt lgkmcnt(0)\n\ts_barrier" ::: "memory");

        int tid = threadIdx.x;
        if (tid < 128) {                 // row pieces: piece q of panel-p rows
            int wrh = tid >> 6, loc = tid & 63;
            float v = red[(wrh * 2 + 0) * 64 + loc] + red[(wrh * 2 + 1) * 64 + loc];
            part[(size_t)q * NROWS + p * 128 + tid] = v;       // coalesced
        } else if (p != q) {             // col pieces: piece p of panel-q rows
            int i2 = tid - 128;
            int wch = i2 >> 6, loc = i2 & 63;
            float v = red[256 + wch * 64 + loc] + red[256 + (2 + wch) * 64 + loc];
            part[(size_t)p * NROWS + q * 128 + i2] = v;        // coalesced
        }

        if (!more) break;
        t += GRID_B; p = np; q = nq;
    }
}

// ---------------------------------------------------------------------------
// Kernel C: per-row loss: log(sum of 64 pieces) - pos_dot*ln2
// (zn is scaled so dot = 2*log2e*cos; 2*cos = dot*ln2)
// part gather is lane-strided (32 KB stride) but part is 2 MB -> L2/L3.
// ---------------------------------------------------------------------------
__global__ void rowloss_kernel(const unsigned short* __restrict__ zn,
                               const float* __restrict__ part,
                               float* __restrict__ cpart) {
    int wave = threadIdx.x >> 6;
    int lane = threadIdx.x & 63;
    float wsum = 0.0f;
#pragma unroll 1
    for (int it = 0; it < 8; ++it) {
        int r = blockIdx.x * 32 + wave * 8 + it;
        ushort4 za = reinterpret_cast<const ushort4*>(zn + (size_t)r * DIM)[lane];
        ushort4 zb = reinterpret_cast<const ushort4*>(zn + (size_t)(r ^ BATCH) * DIM)[lane];
        float dot = bf2f(za.x) * bf2f(zb.x) + bf2f(za.y) * bf2f(zb.y) +
                    bf2f(za.z) * bf2f(zb.z) + bf2f(za.w) * bf2f(zb.w);
#pragma unroll
        for (int m = 1; m < 64; m <<= 1) dot += __shfl_xor(dot, m);
        float den = part[(size_t)lane * NROWS + r];
#pragma unroll
        for (int m = 1; m < 64; m <<= 1) den += __shfl_xor(den, m);
        if (lane == 0) wsum += logf(den) - dot * LN2F;
    }
    __shared__ float red[4];
    if (lane == 0) red[wave] = wsum;
    __syncthreads();
    if (threadIdx.x == 0)
        cpart[blockIdx.x] = red[0] + red[1] + red[2] + red[3];
}

// ---------------------------------------------------------------------------
// Kernel D: final reduction of 256 block partials -> scalar loss / n
// ---------------------------------------------------------------------------
__global__ void final_kernel(const float* __restrict__ cpart,
                             float* __restrict__ out) {
    int lane = threadIdx.x & 63;
    int wave = threadIdx.x >> 6;
    double v = (double)cpart[threadIdx.x];
#pragma unroll
    for (int m = 1; m < 64; m <<= 1) v += __shfl_xor(v, m);
    __shared__ double red[4];
    if (lane == 0) red[wave] = v;
    __syncthreads();
    if (threadIdx.x == 0)
        out[0] = (float)((red[0] + red[1] + red[2] + red[3]) / (double)NROWS);
}

// ---------------------------------------------------------------------------
extern "C" void kernel_launch(void* const* d_in, const int* in_sizes, int n_in,
                              void* d_out, int out_size, void* d_ws, size_t ws_size,
                              hipStream_t stream) {
    const float* z_i = (const float*)d_in[0];
    const float* z_j = (const float*)d_in[1];
    float* out = (float*)d_out;
    char* ws = (char*)d_ws;

    unsigned short* zn = (unsigned short*)ws;                              // 4 MB
    unsigned short* pk = (unsigned short*)(ws + (size_t)NROWS * DIM * 2);  // 4 MB
    float* part  = (float*)(ws + 2 * (size_t)NROWS * DIM * 2);             // 2 MB
    float* cpart = (float*)(ws + 2 * (size_t)NROWS * DIM * 2
                               + (size_t)NP * NROWS * 4);

    normalize_kernel<<<NROWS / 4, 256, 0, stream>>>(z_i, z_j, zn, pk);
    simloss_kernel<<<GRID_B, 256, 0, stream>>>(pk, part);
    rowloss_kernel<<<NROWS / 32, 256, 0, stream>>>(zn, part, cpart);
    final_kernel<<<1, 256, 0, stream>>>(cpart, out);
}

// Round 8
// 55.347 us; speedup vs baseline: 1.1138x; 1.0767x over previous
//
#include <hip/hip_runtime.h>
#include <hip/hip_bf16.h>
#include <math.h>

#define BATCH 4096
#define NROWS 8192
#define DIM 256
#define NP 64                         // 128-row panels
#define NBLK (NP * (NP + 1) / 2)      // 2080 triangular tiles
#define NPIECE (2 * NP)               // 128 denominator pieces per row

// zn scale c with c^2 = 2*log2(e): sim_scaled = c^2*cos = 2*log2e*cos,
// so exp2(sim_scaled) = e^{2 cos} directly.
#define ZN_SCALE 1.698643600577466f   // sqrt(2.8853900817779268)
#define LN2F 0.6931471805599453f

typedef __attribute__((ext_vector_type(4))) float f32x4;
typedef __attribute__((ext_vector_type(8))) short short8;

#if defined(__has_builtin)
#if __has_builtin(__builtin_amdgcn_exp2f)
#define EXP2F(x) __builtin_amdgcn_exp2f(x)
#endif
#endif
#ifndef EXP2F
#define EXP2F(x) __expf(LN2F * (x))
#endif

static __device__ __forceinline__ unsigned short f2bf(float x) {
    __hip_bfloat16 h = __float2bfloat16(x);
    return *reinterpret_cast<unsigned short*>(&h);
}
static __device__ __forceinline__ float bf2f(unsigned short u) {
    union { unsigned int i; float f; } x;
    x.i = ((unsigned int)u) << 16;
    return x.f;
}

// ---------------------------------------------------------------------------
// Kernel A: concat + L2-normalize + scale, write row-major (zn) AND
// MFMA-fragment-packed (pk) layouts.
// pk: element (row r, dim e) lives at granule g*8 + (e&7), where
//     g = ((r>>4)*8 + (e>>5))*64 + ((e&31)>>3)*16 + (r&15)
// => one 1KB granule per (16-row x 32-k) MFMA fragment, in exact lane order,
//    so a fragment load is ONE coalesced global_load_dwordx4 per lane.
// ---------------------------------------------------------------------------
__global__ void normalize_kernel(const float* __restrict__ z_i,
                                 const float* __restrict__ z_j,
                                 unsigned short* __restrict__ zn,
                                 unsigned short* __restrict__ pk) {
    int wid  = (blockIdx.x * blockDim.x + threadIdx.x) >> 6;   // row
    int lane = threadIdx.x & 63;
    if (wid >= NROWS) return;
    const float* src = (wid < BATCH) ? (z_i + (size_t)wid * DIM)
                                     : (z_j + (size_t)(wid - BATCH) * DIM);
    float4 v = reinterpret_cast<const float4*>(src)[lane];
    float ss = v.x * v.x + v.y * v.y + v.z * v.z + v.w * v.w;
#pragma unroll
    for (int m = 1; m < 64; m <<= 1) ss += __shfl_xor(ss, m);
    float inv = ZN_SCALE / fmaxf(sqrtf(ss), 1e-8f);
    ushort4 o;
    o.x = f2bf(v.x * inv);
    o.y = f2bf(v.y * inv);
    o.z = f2bf(v.z * inv);
    o.w = f2bf(v.w * inv);
    reinterpret_cast<ushort4*>(zn + (size_t)wid * DIM)[lane] = o;
    size_t g = ((size_t)(wid >> 4) * 8 + (lane >> 3)) * 64
             + ((lane & 7) >> 1) * 16 + (wid & 15);
    *reinterpret_cast<ushort4*>(pk + g * 8 + (lane & 1) * 4) = o;
}

// ---------------------------------------------------------------------------
// Kernel B: symmetric fused sim-GEMM + sum-of-exp — NO LDS, NO barriers.
// Grid: 2080 blocks = upper-triangle (p,q) 128x128 tiles. Block = 4 waves
// (2x2); each wave computes its 64x64 quadrant entirely from registers:
// fragments loaded straight from pk (1KB coalesced dwordx4 per fragment,
// L2/L3-resident), double-buffered, MFMA:load = 2:1. Waves are fully
// independent -> latency hidden by ILP + TLP, no lockstep.
// Each wave writes its own denominator pieces:
//   row pieces: piece q*2+wc for rows of panel p   (all tiles)
//   col pieces: piece p*2+wr for rows of panel q   (p!=q, via symmetry)
// => every row's 128 pieces are written exactly once; no zero-init needed.
// ---------------------------------------------------------------------------
__device__ __forceinline__ void unrank_tile(int t, int& p, int& q) {
    int pp = (int)((129.0f - sqrtf(16641.0f - 8.0f * (float)t)) * 0.5f);
    pp = pp < 0 ? 0 : (pp > 63 ? 63 : pp);
    while (pp > 0 && t < pp * (129 - pp) / 2) --pp;
    while (pp < 63 && t >= (pp + 1) * (128 - pp) / 2) ++pp;
    p = pp;
    q = pp + (t - pp * (129 - pp) / 2);
}

__device__ __forceinline__ void ld_frags(const char* baseA, const char* baseB,
                                         int ks, short8 (&A)[4], short8 (&B)[4]) {
#pragma unroll
    for (int m = 0; m < 4; ++m)
        A[m] = *(const short8*)(baseA + m * 8192 + ks * 1024);
#pragma unroll
    for (int n = 0; n < 4; ++n)
        B[n] = *(const short8*)(baseB + n * 8192 + ks * 1024);
}

__device__ __forceinline__ void mm_frags(const short8 (&A)[4], const short8 (&B)[4],
                                         f32x4 (&acc)[4][4]) {
#pragma unroll
    for (int m = 0; m < 4; ++m)
#pragma unroll
        for (int n = 0; n < 4; ++n)
            acc[m][n] = __builtin_amdgcn_mfma_f32_16x16x32_bf16(
                A[m], B[n], acc[m][n], 0, 0, 0);
}

__global__ __launch_bounds__(256, 3)
void simloss_kernel(const unsigned short* __restrict__ pk,
                    float* __restrict__ part /* [NPIECE][NROWS] */) {
    int wave = threadIdx.x >> 6;
    int lane = threadIdx.x & 63;
    int lr = lane & 15;                  // fragment col
    int lk = lane >> 4;                  // fragment row group
    int wr = wave >> 1, wc = wave & 1;
    int p, q;
    unrank_tile(blockIdx.x, p, q);

    const char* pkb = (const char*)pk;
    // wave's A row-tiles: p*8 + wr*4 + m ; B row-tiles: q*8 + wc*4 + n
    // fragment (row-tile rt, kfrag ks) at byte offset (rt*8+ks)*1024 + lane*16
    const char* baseA = pkb + (size_t)(p * 8 + wr * 4) * 8192 + (size_t)lane * 16;
    const char* baseB = pkb + (size_t)(q * 8 + wc * 4) * 8192 + (size_t)lane * 16;

    f32x4 acc[4][4];
#pragma unroll
    for (int m = 0; m < 4; ++m)
#pragma unroll
        for (int n = 0; n < 4; ++n) acc[m][n] = (f32x4){0.f, 0.f, 0.f, 0.f};

    // K = 256 = 8 kfrags of 32; explicit 2-buffer register pipeline.
    short8 A0[4], B0[4], A1[4], B1[4];
    ld_frags(baseA, baseB, 0, A0, B0);
    ld_frags(baseA, baseB, 1, A1, B1);
    mm_frags(A0, B0, acc);
    ld_frags(baseA, baseB, 2, A0, B0);
    mm_frags(A1, B1, acc);
    ld_frags(baseA, baseB, 3, A1, B1);
    mm_frags(A0, B0, acc);
    ld_frags(baseA, baseB, 4, A0, B0);
    mm_frags(A1, B1, acc);
    ld_frags(baseA, baseB, 5, A1, B1);
    mm_frags(A0, B0, acc);
    ld_frags(baseA, baseB, 6, A0, B0);
    mm_frags(A1, B1, acc);
    ld_frags(baseA, baseB, 7, A1, B1);
    mm_frags(A0, B0, acc);
    mm_frags(A1, B1, acc);

    // ---- epilogue: exp2, diag-zero, row sums + (p!=q) col sums ----
    int R0 = p * 128 + wr * 64;
    int C0 = q * 128 + wc * 64;
    float dacc[4][4];
#pragma unroll
    for (int m = 0; m < 4; ++m)
#pragma unroll
        for (int j = 0; j < 4; ++j) dacc[m][j] = 0.f;
    float cacc[4] = {0.f, 0.f, 0.f, 0.f};

#pragma unroll
    for (int m = 0; m < 4; ++m) {
        int gr = R0 + m * 16;
#pragma unroll
        for (int n = 0; n < 4; ++n) {
            int gc = C0 + n * 16;
            bool diagf = (gr == gc);      // uniform per fragment
            float cs_ = 0.f;
#pragma unroll
            for (int j = 0; j < 4; ++j) {
                float e = EXP2F(acc[m][n][j]);
                if (diagf && lr == lk * 4 + j) e = 0.0f;
                dacc[m][j] += e;
                cs_ += e;
            }
            cacc[n] += cs_;
        }
    }

    // row pieces: reduce over 16 col-lanes (lr); lanes lr==0 write
#pragma unroll
    for (int m = 0; m < 4; ++m)
#pragma unroll
        for (int j = 0; j < 4; ++j) {
            float v = dacc[m][j];
            v += __shfl_xor(v, 1);
            v += __shfl_xor(v, 2);
            v += __shfl_xor(v, 4);
            v += __shfl_xor(v, 8);
            if (lr == 0)
                part[(size_t)(q * 2 + wc) * NROWS + R0 + m * 16 + lk * 4 + j] = v;
        }
    // col pieces: reduce over the 4 lk groups; lanes lk==0 (0..15) write
    if (p != q) {
#pragma unroll
        for (int n = 0; n < 4; ++n) {
            float c = cacc[n];
            c += __shfl_xor(c, 16);
            c += __shfl_xor(c, 32);
            if (lk == 0)
                part[(size_t)(p * 2 + wr) * NROWS + C0 + n * 16 + lr] = c;
        }
    }
}

// ---------------------------------------------------------------------------
// Kernel C: per-row loss: log(sum of 128 pieces) - pos_dot*ln2
// (zn is scaled so dot = 2*log2e*cos; 2*cos = dot*ln2)
// piece gathers are lane-strided but part (4 MB) is L2/L3-resident.
// ---------------------------------------------------------------------------
__global__ void rowloss_kernel(const unsigned short* __restrict__ zn,
                               const float* __restrict__ part,
                               float* __restrict__ cpart) {
    int wave = threadIdx.x >> 6;
    int lane = threadIdx.x & 63;
    float wsum = 0.0f;
#pragma unroll 1
    for (int it = 0; it < 8; ++it) {
        int r = blockIdx.x * 32 + wave * 8 + it;
        ushort4 za = reinterpret_cast<const ushort4*>(zn + (size_t)r * DIM)[lane];
        ushort4 zb = reinterpret_cast<const ushort4*>(zn + (size_t)(r ^ BATCH) * DIM)[lane];
        float dot = bf2f(za.x) * bf2f(zb.x) + bf2f(za.y) * bf2f(zb.y) +
                    bf2f(za.z) * bf2f(zb.z) + bf2f(za.w) * bf2f(zb.w);
#pragma unroll
        for (int m = 1; m < 64; m <<= 1) dot += __shfl_xor(dot, m);
        float den = part[(size_t)lane * NROWS + r]
                  + part[(size_t)(lane + 64) * NROWS + r];
#pragma unroll
        for (int m = 1; m < 64; m <<= 1) den += __shfl_xor(den, m);
        if (lane == 0) wsum += logf(den) - dot * LN2F;
    }
    __shared__ float red[4];
    if (lane == 0) red[wave] = wsum;
    __syncthreads();
    if (threadIdx.x == 0)
        cpart[blockIdx.x] = red[0] + red[1] + red[2] + red[3];
}

// ---------------------------------------------------------------------------
// Kernel D: final reduction of 256 block partials -> scalar loss / n
// ---------------------------------------------------------------------------
__global__ void final_kernel(const float* __restrict__ cpart,
                             float* __restrict__ out) {
    int lane = threadIdx.x & 63;
    int wave = threadIdx.x >> 6;
    double v = (double)cpart[threadIdx.x];
#pragma unroll
    for (int m = 1; m < 64; m <<= 1) v += __shfl_xor(v, m);
    __shared__ double red[4];
    if (lane == 0) red[wave] = v;
    __syncthreads();
    if (threadIdx.x == 0)
        out[0] = (float)((red[0] + red[1] + red[2] + red[3]) / (double)NROWS);
}

// ---------------------------------------------------------------------------
extern "C" void kernel_launch(void* const* d_in, const int* in_sizes, int n_in,
                              void* d_out, int out_size, void* d_ws, size_t ws_size,
                              hipStream_t stream) {
    const float* z_i = (const float*)d_in[0];
    const float* z_j = (const float*)d_in[1];
    float* out = (float*)d_out;
    char* ws = (char*)d_ws;

    unsigned short* zn = (unsigned short*)ws;                              // 4 MB
    unsigned short* pk = (unsigned short*)(ws + (size_t)NROWS * DIM * 2);  // 4 MB
    float* part  = (float*)(ws + 2 * (size_t)NROWS * DIM * 2);             // 4 MB
    float* cpart = (float*)(ws + 2 * (size_t)NROWS * DIM * 2
                               + (size_t)NPIECE * NROWS * 4);

    normalize_kernel<<<NROWS / 4, 256, 0, stream>>>(z_i, z_j, zn, pk);
    simloss_kernel<<<NBLK, 256, 0, stream>>>(pk, part);
    rowloss_kernel<<<NROWS / 32, 256, 0, stream>>>(zn, part, cpart);
    final_kernel<<<1, 256, 0, stream>>>(cpart, out);
}

// Round 9
// 53.267 us; speedup vs baseline: 1.1573x; 1.0391x over previous
//
#include <hip/hip_runtime.h>
#include <hip/hip_bf16.h>
#include <math.h>

#define BATCH 4096
#define NROWS 8192
#define DIM 256
#define NP 64                         // 128-row panels
#define NBLK (NP * (NP + 1) / 2)      // 2080 triangular tiles
#define NPIECE (2 * NP)               // 128 denominator pieces per row

// zn scale c with c^2 = 2*log2(e): sim_scaled = c^2*cos = 2*log2e*cos,
// so exp2(sim_scaled) = e^{2 cos} directly.
#define ZN_SCALE 1.698643600577466f   // sqrt(2.8853900817779268)
#define LN2F 0.6931471805599453f

typedef __attribute__((ext_vector_type(4))) float f32x4;
typedef __attribute__((ext_vector_type(8))) short short8;

#if defined(__has_builtin)
#if __has_builtin(__builtin_amdgcn_exp2f)
#define EXP2F(x) __builtin_amdgcn_exp2f(x)
#endif
#endif
#ifndef EXP2F
#define EXP2F(x) __expf(LN2F * (x))
#endif

static __device__ __forceinline__ unsigned short f2bf(float x) {
    __hip_bfloat16 h = __float2bfloat16(x);
    return *reinterpret_cast<unsigned short*>(&h);
}
static __device__ __forceinline__ float bf2f(unsigned short u) {
    union { unsigned int i; float f; } x;
    x.i = ((unsigned int)u) << 16;
    return x.f;
}

// ---------------------------------------------------------------------------
// Kernel A: concat + L2-normalize + scale, write row-major (zn) AND
// MFMA-fragment-packed (pk) layouts.
// pk: element (row r, dim e) lives at granule g*8 + (e&7), where
//     g = ((r>>4)*8 + (e>>5))*64 + ((e&31)>>3)*16 + (r&15)
// => one 1KB granule per (16-row x 32-k) MFMA fragment, in exact lane order,
//    so a fragment load is ONE coalesced global_load_dwordx4 per lane.
// ---------------------------------------------------------------------------
__global__ void normalize_kernel(const float* __restrict__ z_i,
                                 const float* __restrict__ z_j,
                                 unsigned short* __restrict__ zn,
                                 unsigned short* __restrict__ pk) {
    int wid  = (blockIdx.x * blockDim.x + threadIdx.x) >> 6;   // row
    int lane = threadIdx.x & 63;
    if (wid >= NROWS) return;
    const float* src = (wid < BATCH) ? (z_i + (size_t)wid * DIM)
                                     : (z_j + (size_t)(wid - BATCH) * DIM);
    float4 v = reinterpret_cast<const float4*>(src)[lane];
    float ss = v.x * v.x + v.y * v.y + v.z * v.z + v.w * v.w;
#pragma unroll
    for (int m = 1; m < 64; m <<= 1) ss += __shfl_xor(ss, m);
    float inv = ZN_SCALE / fmaxf(sqrtf(ss), 1e-8f);
    ushort4 o;
    o.x = f2bf(v.x * inv);
    o.y = f2bf(v.y * inv);
    o.z = f2bf(v.z * inv);
    o.w = f2bf(v.w * inv);
    reinterpret_cast<ushort4*>(zn + (size_t)wid * DIM)[lane] = o;
    size_t g = ((size_t)(wid >> 4) * 8 + (lane >> 3)) * 64
             + ((lane & 7) >> 1) * 16 + (wid & 15);
    *reinterpret_cast<ushort4*>(pk + g * 8 + (lane & 1) * 4) = o;
}

// ---------------------------------------------------------------------------
// Kernel B: symmetric fused sim-GEMM + sum-of-exp — NO LDS data staging.
// Grid: 2080 blocks, XCD-swizzled so each XCD walks ~260 CONSECUTIVE
// triangle tiles (A-panel reused within one XCD's L2).
// Block = 4 waves (2x2), wave = 64x64 quadrant, fragments straight from pk
// (1KB coalesced dwordx4 per fragment), register double-buffered.
// s_barrier per K-phase keeps the block's waves aligned so the wave pairs'
// IDENTICAL fragment loads merge in L1/MSHR (halves L2 demand).
// part written with nontemporal stores to keep pk L2-resident.
//   row pieces: piece q*2+wc for rows of panel p   (all tiles)
//   col pieces: piece p*2+wr for rows of panel q   (p!=q, via symmetry)
// ---------------------------------------------------------------------------
__device__ __forceinline__ void unrank_tile(int t, int& p, int& q) {
    int pp = (int)((129.0f - sqrtf(16641.0f - 8.0f * (float)t)) * 0.5f);
    pp = pp < 0 ? 0 : (pp > 63 ? 63 : pp);
    while (pp > 0 && t < pp * (129 - pp) / 2) --pp;
    while (pp < 63 && t >= (pp + 1) * (128 - pp) / 2) ++pp;
    p = pp;
    q = pp + (t - pp * (129 - pp) / 2);
}

__device__ __forceinline__ void ld_frags(const char* baseA, const char* baseB,
                                         int ks, short8 (&A)[4], short8 (&B)[4]) {
#pragma unroll
    for (int m = 0; m < 4; ++m)
        A[m] = *(const short8*)(baseA + m * 8192 + ks * 1024);
#pragma unroll
    for (int n = 0; n < 4; ++n)
        B[n] = *(const short8*)(baseB + n * 8192 + ks * 1024);
}

__device__ __forceinline__ void mm_frags(const short8 (&A)[4], const short8 (&B)[4],
                                         f32x4 (&acc)[4][4]) {
#pragma unroll
    for (int m = 0; m < 4; ++m)
#pragma unroll
        for (int n = 0; n < 4; ++n)
            acc[m][n] = __builtin_amdgcn_mfma_f32_16x16x32_bf16(
                A[m], B[n], acc[m][n], 0, 0, 0);
}

#define PHASE_BAR() __builtin_amdgcn_s_barrier()

__global__ __launch_bounds__(256, 3)
void simloss_kernel(const unsigned short* __restrict__ pk,
                    float* __restrict__ part /* [NPIECE][NROWS] */) {
    int wave = threadIdx.x >> 6;
    int lane = threadIdx.x & 63;
    int lr = lane & 15;                  // fragment col
    int lk = lane >> 4;                  // fragment row group
    int wr = wave >> 1, wc = wave & 1;
    // XCD-contiguous swizzle: 2080 = 8 XCDs x 260 consecutive tiles
    int bt = (int)blockIdx.x;
    int t = (bt & 7) * 260 + (bt >> 3);
    int p, q;
    unrank_tile(t, p, q);

    const char* pkb = (const char*)pk;
    const char* baseA = pkb + (size_t)(p * 8 + wr * 4) * 8192 + (size_t)lane * 16;
    const char* baseB = pkb + (size_t)(q * 8 + wc * 4) * 8192 + (size_t)lane * 16;

    f32x4 acc[4][4];
#pragma unroll
    for (int m = 0; m < 4; ++m)
#pragma unroll
        for (int n = 0; n < 4; ++n) acc[m][n] = (f32x4){0.f, 0.f, 0.f, 0.f};

    // K = 256 = 8 kfrags of 32; register double-buffer; barrier per phase
    // aligns the 4 waves so duplicate loads dedup in L1.
    short8 A0[4], B0[4], A1[4], B1[4];
    ld_frags(baseA, baseB, 0, A0, B0);
    PHASE_BAR(); ld_frags(baseA, baseB, 1, A1, B1); mm_frags(A0, B0, acc);
    PHASE_BAR(); ld_frags(baseA, baseB, 2, A0, B0); mm_frags(A1, B1, acc);
    PHASE_BAR(); ld_frags(baseA, baseB, 3, A1, B1); mm_frags(A0, B0, acc);
    PHASE_BAR(); ld_frags(baseA, baseB, 4, A0, B0); mm_frags(A1, B1, acc);
    PHASE_BAR(); ld_frags(baseA, baseB, 5, A1, B1); mm_frags(A0, B0, acc);
    PHASE_BAR(); ld_frags(baseA, baseB, 6, A0, B0); mm_frags(A1, B1, acc);
    PHASE_BAR(); ld_frags(baseA, baseB, 7, A1, B1); mm_frags(A0, B0, acc);
    mm_frags(A1, B1, acc);

    // ---- epilogue: exp2, diag-zero, row sums + (p!=q) col sums ----
    int R0 = p * 128 + wr * 64;
    int C0 = q * 128 + wc * 64;
    float dacc[4][4];
#pragma unroll
    for (int m = 0; m < 4; ++m)
#pragma unroll
        for (int j = 0; j < 4; ++j) dacc[m][j] = 0.f;
    float cacc[4] = {0.f, 0.f, 0.f, 0.f};

#pragma unroll
    for (int m = 0; m < 4; ++m) {
        int gr = R0 + m * 16;
#pragma unroll
        for (int n = 0; n < 4; ++n) {
            int gc = C0 + n * 16;
            bool diagf = (gr == gc);      // uniform per fragment
            float cs_ = 0.f;
#pragma unroll
            for (int j = 0; j < 4; ++j) {
                float e = EXP2F(acc[m][n][j]);
                if (diagf && lr == lk * 4 + j) e = 0.0f;
                dacc[m][j] += e;
                cs_ += e;
            }
            cacc[n] += cs_;
        }
    }

    // row pieces: reduce over 16 col-lanes (lr); lanes lr==0 write (nt)
#pragma unroll
    for (int m = 0; m < 4; ++m)
#pragma unroll
        for (int j = 0; j < 4; ++j) {
            float v = dacc[m][j];
            v += __shfl_xor(v, 1);
            v += __shfl_xor(v, 2);
            v += __shfl_xor(v, 4);
            v += __shfl_xor(v, 8);
            if (lr == 0)
                __builtin_nontemporal_store(v,
                    &part[(size_t)(q * 2 + wc) * NROWS + R0 + m * 16 + lk * 4 + j]);
        }
    // col pieces: reduce over the 4 lk groups; lanes lk==0 (0..15) write (nt)
    if (p != q) {
#pragma unroll
        for (int n = 0; n < 4; ++n) {
            float c = cacc[n];
            c += __shfl_xor(c, 16);
            c += __shfl_xor(c, 32);
            if (lk == 0)
                __builtin_nontemporal_store(c,
                    &part[(size_t)(p * 2 + wr) * NROWS + C0 + n * 16 + lr]);
        }
    }
}

// ---------------------------------------------------------------------------
// Kernel C: per-row loss: log(sum of 128 pieces) - pos_dot*ln2
// One row per wave (2048 blocks) -> no serial latency chain.
// ---------------------------------------------------------------------------
__global__ void rowloss_kernel(const unsigned short* __restrict__ zn,
                               const float* __restrict__ part,
                               float* __restrict__ cpart /* [NROWS] */) {
    int wave = threadIdx.x >> 6;
    int lane = threadIdx.x & 63;
    int r = blockIdx.x * 4 + wave;
    ushort4 za = reinterpret_cast<const ushort4*>(zn + (size_t)r * DIM)[lane];
    ushort4 zb = reinterpret_cast<const ushort4*>(zn + (size_t)(r ^ BATCH) * DIM)[lane];
    float dot = bf2f(za.x) * bf2f(zb.x) + bf2f(za.y) * bf2f(zb.y) +
                bf2f(za.z) * bf2f(zb.z) + bf2f(za.w) * bf2f(zb.w);
#pragma unroll
    for (int m = 1; m < 64; m <<= 1) dot += __shfl_xor(dot, m);
    float den = part[(size_t)lane * NROWS + r]
              + part[(size_t)(lane + 64) * NROWS + r];
#pragma unroll
    for (int m = 1; m < 64; m <<= 1) den += __shfl_xor(den, m);
    if (lane == 0) cpart[r] = logf(den) - dot * LN2F;
}

// ---------------------------------------------------------------------------
// Kernel D: final reduction of 8192 row losses -> scalar loss / n
// ---------------------------------------------------------------------------
__global__ void final_kernel(const float* __restrict__ cpart,
                             float* __restrict__ out) {
    int lane = threadIdx.x & 63;
    int wave = threadIdx.x >> 6;
    double v = 0.0;
#pragma unroll
    for (int k = 0; k < 32; ++k)
        v += (double)cpart[threadIdx.x + k * 256];
#pragma unroll
    for (int m = 1; m < 64; m <<= 1) v += __shfl_xor(v, m);
    __shared__ double red[4];
    if (lane == 0) red[wave] = v;
    __syncthreads();
    if (threadIdx.x == 0)
        out[0] = (float)((red[0] + red[1] + red[2] + red[3]) / (double)NROWS);
}

// ---------------------------------------------------------------------------
extern "C" void kernel_launch(void* const* d_in, const int* in_sizes, int n_in,
                              void* d_out, int out_size, void* d_ws, size_t ws_size,
                              hipStream_t stream) {
    const float* z_i = (const float*)d_in[0];
    const float* z_j = (const float*)d_in[1];
    float* out = (float*)d_out;
    char* ws = (char*)d_ws;

    unsigned short* zn = (unsigned short*)ws;                              // 4 MB
    unsigned short* pk = (unsigned short*)(ws + (size_t)NROWS * DIM * 2);  // 4 MB
    float* part  = (float*)(ws + 2 * (size_t)NROWS * DIM * 2);             // 4 MB
    float* cpart = (float*)(ws + 2 * (size_t)NROWS * DIM * 2
                               + (size_t)NPIECE * NROWS * 4);              // 32 KB

    normalize_kernel<<<NROWS / 4, 256, 0, stream>>>(z_i, z_j, zn, pk);
    simloss_kernel<<<NBLK, 256, 0, stream>>>(pk, part);
    rowloss_kernel<<<NROWS / 4, 256, 0, stream>>>(zn, part, cpart);
    final_kernel<<<1, 256, 0, stream>>>(cpart, out);
}